// Round 10
// baseline (107.679 us; speedup 1.0000x reference)
//
#include <hip/hip_runtime.h>

#define BS 4096
#define LL 512
#define NCH 16                // chunks per batch (2 per wave)
#define CS (LL / NCH)         // 32 steps per chunk
#define START_TAG 1
#define END_TAG 2
#define BIASF 4.5f            // per-applied-step 2^-BIASF scaling (restored exactly)
#define L2E 1.44269504f

typedef float f32x4 __attribute__((ext_vector_type(4)));
typedef short s16x4 __attribute__((ext_vector_type(4)));
union BF4 { unsigned u[2]; s16x4 s; };

__device__ __forceinline__ unsigned cvt_pk_bf16(float lo, float hi) {
    unsigned r;
    asm("v_cvt_pk_bf16_f32 %0, %1, %2" : "=v"(r) : "v"(lo), "v"(hi));
    return r;
}
__device__ __forceinline__ float blo(unsigned u) { return __uint_as_float(u << 16); }
__device__ __forceinline__ float bhi(unsigned u) { return __uint_as_float(u & 0xFFFF0000u); }

// Block = one batch, 8 waves; wave wv owns TWO 32-step chunks (2wv, 2wv+1) run
// as interleaved independent MFMA chains (latency hiding via ILP):
//   M_c = prod_{t active} diag(e^{em_t} 2^-BIASF) * E^T      (E = exp(tr))
// Scales are mask-compacted into LDS at staging (branch-free chain loop).
// bf16 state (f32 exponent range — validated r3-r8), exact pow2 renorm mid-chunk.
__global__ __launch_bounds__(512, 4) void crf_dual(
    const float* __restrict__ em, const int* __restrict__ tg,
    const float* __restrict__ mk, const float* __restrict__ tr,
    float* __restrict__ out)
{
    __shared__ float sE[LL * 16];        // 32 KB compacted f32 scales
    __shared__ float sP[NCH][16][16];    // 16 KB chunk matrices
    __shared__ float sO[NCH];            // per-chunk renorm exponent sums
    __shared__ float sSc[8], sCnt[8];

    const int tid  = threadIdx.x;
    const int wv   = tid >> 6;
    const int lane = tid & 63;
    const int j    = lane & 15;
    const int q    = lane >> 4;
    const long bb  = (long)blockIdx.x * LL;
    const int  t0  = wv * 64;            // this wave's 64 steps (2 chunks)

    // tags dtype detect (validated): 16 u64 words all <16 => int64 layout
    int is64 = 1;
    {
        const unsigned long long* t64 = (const unsigned long long*)tg;
#pragma unroll
        for (int i = 0; i < 16; ++i) is64 &= (t64[i] < 16ull) ? 1 : 0;
    }
    const int esz = is64 ? 2 : 1;

    // ---- mask ballot: lane = step; lo 32 = chunk A, hi 32 = chunk B ----
    const float mlane = mk[bb + t0 + lane];
    const unsigned long long bal = __ballot(mlane > 0.f);
    const unsigned balA = (unsigned)bal, balB = (unsigned)(bal >> 32);
    const int nA = __popc(balA), nB = __popc(balB);

    // ---- staging: coalesced em loads -> exp2 -> mask-compacted f32 scales ----
    {
        const float* emb = em + ((bb + t0) << 4);
#pragma unroll
        for (int k = 0; k < 4; ++k) {
            const int idx = (lane << 2) + (k << 8);   // float idx in wave region
            const f32x4 v = *(const f32x4*)(emb + idx);
            const int st = idx >> 4;                  // step 0..63 (wave-local)
            const int rg = lane & 3;                  // row group
            f32x4 e;
            e.x = exp2f(fmaf(v.x, L2E, -BIASF));
            e.y = exp2f(fmaf(v.y, L2E, -BIASF));
            e.z = exp2f(fmaf(v.z, L2E, -BIASF));
            e.w = exp2f(fmaf(v.w, L2E, -BIASF));
            const int half = st >> 5, stl = st & 31;
            const unsigned bm = half ? balB : balA;
            if ((bm >> stl) & 1u) {
                const int slot = __popc(bm & ((1u << stl) - 1u));
                *(f32x4*)(sE + (2 * wv + half) * (CS * 16) + slot * 16 + rg * 4) = e;
            }
        }
    }

    // ---- path score + mask count: 1 step per lane (L1-hot gathers) ----
    {
        const int t    = t0 + lane;
        const int tcur = tg[(bb + t) * esz];
        const int tpv  = (t == 0) ? START_TAG : (int)tg[(bb + t - 1) * esz];
        const float scm = (t == 0) ? 1.f : mlane;
        float part  = fmaf(em[((bb + t) << 4) + tcur] + tr[tpv * 16 + tcur], scm, 0.f);
        float cpart = mlane;
#pragma unroll
        for (int o = 1; o <= 32; o <<= 1) {
            part  += __shfl_xor(part, o);
            cpart += __shfl_xor(cpart, o);
        }
        if (lane == 0) { sSc[wv] = part; sCnt[wv] = cpart; }
    }

    // ---- static A = E^T: lane (j,q) holds A[j][4q+i] = exp(tr[4q+i][j]) ----
    BF4 Ab;
    {
        float Ef[4];
#pragma unroll
        for (int i = 0; i < 4; ++i)
            Ef[i] = expf(tr[(q * 4 + i) * 16 + j]);   // exp(-1000) -> exact 0
        Ab.u[0] = cvt_pk_bf16(Ef[0], Ef[1]);
        Ab.u[1] = cvt_pk_bf16(Ef[2], Ef[3]);
    }

    // ---- dual interleaved chains, branch-free over compacted steps ----
    const unsigned idlo = ((q*4+0 == j) ? 0x3F80u : 0u) | (((q*4+1 == j) ? 0x3F80u : 0u) << 16);
    const unsigned idhi = ((q*4+2 == j) ? 0x3F80u : 0u) | (((q*4+3 == j) ? 0x3F80u : 0u) << 16);
    unsigned x01 = idlo, x23 = idhi;     // chain A state (bf16 packed)
    unsigned y01 = idlo, y23 = idhi;     // chain B state
    float e2fA = 0.f, e2fB = 0.f;
    const float* pEA = sE + (2 * wv + 0) * (CS * 16) + (q << 2);
    const float* pEB = sE + (2 * wv + 1) * (CS * 16) + (q << 2);

#define STEPX(P01, P23, PE, I) { \
        const f32x4 s4 = *(const f32x4*)((PE) + (I) * 16); \
        BF4 Bf; Bf.u[0] = P01; Bf.u[1] = P23; \
        f32x4 z = {0.f, 0.f, 0.f, 0.f}; \
        f32x4 d = __builtin_amdgcn_mfma_f32_16x16x16bf16_1k(Ab.s, Bf.s, z, 0, 0, 0); \
        P01 = cvt_pk_bf16(d[0] * s4.x, d[1] * s4.y); \
        P23 = cvt_pk_bf16(d[2] * s4.z, d[3] * s4.w); }

#define RENX(P01, P23, E2F) { \
        const float v0 = blo(P01), v1 = bhi(P01), v2 = blo(P23), v3 = bhi(P23); \
        float mm = fmaxf(fmaxf(v0, v1), fmaxf(v2, v3)); \
        for (int o = 1; o <= 32; o <<= 1) mm = fmaxf(mm, __shfl_xor(mm, o)); \
        if (mm > 0.f) { \
            const int ex = (int)((__float_as_uint(mm) >> 23) & 0xFFu) - 127; \
            const float sre = __uint_as_float((unsigned)(127 - ex) << 23); \
            E2F += (float)ex; \
            P01 = cvt_pk_bf16(v0 * sre, v1 * sre); \
            P23 = cvt_pk_bf16(v2 * sre, v3 * sre); } }

    const int nmin = (nA < nB) ? nA : nB;
    int i = 0;
    for (; i + 4 <= nmin; i += 4) {
#pragma unroll
        for (int s = 0; s < 4; ++s) {
            STEPX(x01, x23, pEA, i + s)
            STEPX(y01, y23, pEB, i + s)
        }
        if (((i + 4) & 15) == 0 && (i + 4) < CS) {   // renorm mid-chunk
            RENX(x01, x23, e2fA)
            RENX(y01, y23, e2fB)
        }
    }
    for (; i < nmin; ++i) { STEPX(x01, x23, pEA, i) STEPX(y01, y23, pEB, i) }
    for (int ia = i; ia < nA; ++ia) STEPX(x01, x23, pEA, ia)
    for (int ib = i; ib < nB; ++ib) STEPX(y01, y23, pEB, ib)

    // ---- chunk matrices -> LDS ----
    sP[2*wv+0][q*4+0][j] = blo(x01); sP[2*wv+0][q*4+1][j] = bhi(x01);
    sP[2*wv+0][q*4+2][j] = blo(x23); sP[2*wv+0][q*4+3][j] = bhi(x23);
    sP[2*wv+1][q*4+0][j] = blo(y01); sP[2*wv+1][q*4+1][j] = bhi(y01);
    sP[2*wv+1][q*4+2][j] = blo(y23); sP[2*wv+1][q*4+3][j] = bhi(y23);
    if (lane == 0) { sO[2*wv] = e2fA; sO[2*wv+1] = e2fB; }
    __syncthreads();

    // ---- combine on lanes 0..15: alpha = M15*...*M0 * ones ----
    if (tid < 16) {
        const int jj = tid;
        float w = 1.f, l2 = 0.f;
#pragma unroll
        for (int c = 0; c < NCH; ++c) {
            float nw = 0.f;
#pragma unroll
            for (int i2 = 0; i2 < 16; ++i2)
                nw = fmaf(sP[c][jj][i2], __shfl(w, i2, 16), nw);
            float m = nw;
#pragma unroll
            for (int o = 1; o <= 8; o <<= 1) m = fmaxf(m, __shfl_xor(m, o, 16));
            m = fmaxf(m, 1e-30f);
            l2 += log2f(m);
            w = nw / m;
        }
        float scT = 0.f, cntT = 0.f, ot = 0.f;
#pragma unroll
        for (int c = 0; c < 8; ++c) { scT += sSc[c]; cntT += sCnt[c]; }
#pragma unroll
        for (int c = 0; c < NCH; ++c) ot += sO[c];
        ot += BIASF * cntT;

        float y = log2f(w) + l2 + ot + tr[jj * 16 + END_TAG] * L2E;
        float m2 = y;
#pragma unroll
        for (int o = 1; o <= 8; o <<= 1) m2 = fmaxf(m2, __shfl_xor(m2, o, 16));
        m2 = fmaxf(m2, -1e30f);
        float e = exp2f(y - m2);
#pragma unroll
        for (int o = 1; o <= 8; o <<= 1) e += __shfl_xor(e, o, 16);
        const float dp = (m2 + log2f(e)) * 0.69314718055994531f;

        if (jj == 0) {
            const int li = (int)cntT - 1;
            const int lt = tg[(bb + li) * esz];
            atomicAdd(out, dp - (scT + tr[lt * 16 + END_TAG]));
        }
    }
}

extern "C" void kernel_launch(void* const* d_in, const int* in_sizes, int n_in,
                              void* d_out, int out_size, void* d_ws, size_t ws_size,
                              hipStream_t stream) {
    const float* em = (const float*)d_in[0];
    const int*   tg = (const int*)d_in[1];
    const float* mk = (const float*)d_in[2];
    const float* tr = (const float*)d_in[3];
    float* out = (float*)d_out;

    hipMemsetAsync(out, 0, sizeof(float), stream);
    crf_dual<<<BS, 512, 0, stream>>>(em, tg, mk, tr, out);
}